// Round 13
// baseline (2425.875 us; speedup 1.0000x reference)
//
#include <hip/hip_runtime.h>
#include <math.h>

#define BB 128
#define TT 2048
#define II 128
#define UU 256
#define OO 128

typedef __attribute__((ext_vector_type(8))) short bf16x8;
typedef __attribute__((ext_vector_type(4))) float f32x4;

#define MFMA16(a, b, cacc) __builtin_amdgcn_mfma_f32_16x16x32_bf16(a, b, cacc, 0, 0, 0)

// LDS-only barrier (rule 18): orders LDS ops without draining vmcnt.
__device__ __forceinline__ void bar_lds() {
    __builtin_amdgcn_sched_barrier(0);
    asm volatile("s_waitcnt lgkmcnt(0)" ::: "memory");
    __builtin_amdgcn_s_barrier();
    __builtin_amdgcn_sched_barrier(0);
}

// float -> bf16 round-to-nearest-even
__device__ __forceinline__ short f2bf(float f) {
    unsigned u = __float_as_uint(f);
    unsigned r = (u + 0x7FFFu + ((u >> 16) & 1u)) >> 16;
    return (short)r;
}

__device__ __forceinline__ bf16x8 loadf8(const float* p) {
    float4 va = *reinterpret_cast<const float4*>(p);
    float4 vb = *reinterpret_cast<const float4*>(p + 4);
    bf16x8 v;
    v[0] = f2bf(va.x); v[1] = f2bf(va.y); v[2] = f2bf(va.z); v[3] = f2bf(va.w);
    v[4] = f2bf(vb.x); v[5] = f2bf(vb.y); v[6] = f2bf(vb.z); v[7] = f2bf(vb.w);
    return v;
}

// ---------------- Persistent fused kernel ---------------------------------
// 256 blocks x 512 thr, ALL co-resident (256 CUs) -> no scheduling deadlock:
// recurrence blocks never wait on workers; workers spin on progress flags.
//   blocks 0-127   : serial recurrence for batch b (r8-exact body, 546ns/step)
//                    + xpdone[b] acquire-gate per xp slab (64 steps)
//                    + prog[b] release per completed slab
//   blocks 128-255 : worker for batch b = bid-128:
//                    phase 1: xp = x.Wih^T + bias, slab by slab -> xpdone[b]
//                    phase 2: readout + mask fix-up, gated on prog[b]
// xp / h_raw / hs share the outH region exactly as rounds 8-11 (validated):
// worker writes xp[t]; recurrence reads xp[t+2] and overwrites [t] with
// h_raw; worker reads h_raw, writes readout, zeroes cols {3,7} in place.
__global__ __launch_bounds__(512, 2) void k_all(
    const float* __restrict__ x, const float* __restrict__ Wih,
    const float* __restrict__ Whh, const float* __restrict__ bih,
    const float* __restrict__ bhh, const float* __restrict__ Wfc,
    const float* __restrict__ bfc, float* __restrict__ outR,
    float* __restrict__ outH, int* __restrict__ flags)
{
    __shared__ __align__(16) short lds16[64 * 256];   // 32 KB (worker tiles)
    const int tid = threadIdx.x;
    const int w = tid >> 6;
    const int lane = tid & 63;
    const int g = lane >> 4;
    const int c = lane & 15;
    int* prog   = flags;          // [128] slabs of h_raw completed
    int* xpdone = flags + 128;    // [128] slabs of xp completed

    if (blockIdx.x < 128) {
        // ================= recurrence block (batch b) =================
        const int b = blockIdx.x;
        short* hbuf = lds16;                       // 2 x 256 bf16
        bf16x8 bq[2][8];
        #pragma unroll
        for (int q2 = 0; q2 < 2; ++q2) {
            const int ub = w * 32 + q2 * 16 + c;
            #pragma unroll
            for (int kt = 0; kt < 8; ++kt)
                bq[q2][kt] = loadf8(&Whh[(size_t)ub * UU + kt * 32 + g * 8]);
        }
        const int q = g & 1;
        const int uxp = w * 32 + q * 16 + c;
        const bool gl = (g < 2);
        const bool kill = (uxp == 3) || (uxp == 7);
        if (tid < 256) reinterpret_cast<int*>(hbuf)[tid] = 0;
        __syncthreads();

        float* rowp = outH + (size_t)b * (size_t)TT * UU;
        // wait for xp slab 0
        while (__hip_atomic_load(&xpdone[b], __ATOMIC_ACQUIRE,
                                 __HIP_MEMORY_SCOPE_AGENT) < 1)
            __builtin_amdgcn_s_sleep(8);
        float xpv = rowp[uxp];
        float xpn = rowp[UU + uxp];

        auto step = [&](int t, int p) {
            int tn = t + 2; tn = (tn < TT) ? tn : (TT - 1);
            if ((tn & 63) == 0) {                  // entering xp slab tn>>6
                const int need = (tn >> 6) + 1;
                while (__hip_atomic_load(&xpdone[b], __ATOMIC_ACQUIRE,
                                         __HIP_MEMORY_SCOPE_AGENT) < need)
                    __builtin_amdgcn_s_sleep(2);
            }
            float xpn2 = rowp[(size_t)tn * UU + uxp];
            const bf16x8* hb = reinterpret_cast<const bf16x8*>(hbuf + p * 256);
            f32x4 acc0[4], acc1[4];
            #pragma unroll
            for (int i = 0; i < 4; ++i) {
                acc0[i] = (f32x4){0.f, 0.f, 0.f, 0.f};
                acc1[i] = (f32x4){0.f, 0.f, 0.f, 0.f};
            }
            #pragma unroll
            for (int kt = 0; kt < 8; ++kt) {
                bf16x8 a = hb[kt * 4 + g];
                acc0[kt & 3] = MFMA16(a, bq[0][kt], acc0[kt & 3]);
                acc1[kt & 3] = MFMA16(a, bq[1][kt], acc1[kt & 3]);
            }
            float d0 = (acc0[0][0] + acc0[1][0]) + (acc0[2][0] + acc0[3][0]);
            float d1 = (acc1[0][0] + acc1[1][0]) + (acc1[2][0] + acc1[3][0]);
            float Dres = q ? d1 : d0;
            float s = Dres + xpv;
            float hr = 1.0f - 2.0f / (__expf(2.0f * s) + 1.0f);
            if (gl) {
                rowp[(size_t)t * UU + uxp] = hr;                 // h_raw
            } else {
                hbuf[(p ^ 1) * 256 + uxp] = kill ? (short)0 : f2bf(hr);
            }
            const bool flag = ((t & 63) == 63);
            if (flag) asm volatile("s_waitcnt vmcnt(0)" ::: "memory");
            bar_lds();
            if (flag && tid == 0)
                __hip_atomic_store(&prog[b], (t >> 6) + 1, __ATOMIC_RELEASE,
                                   __HIP_MEMORY_SCOPE_AGENT);
            xpv = xpn; xpn = xpn2;
        };
        for (int t = 0; t < TT; t += 2) { step(t, 0); step(t + 1, 1); }
    } else {
        // ================= worker block (batch b) =================
        const int b = blockIdx.x - 128;
        const int nrole = w & 3;                   // n-range role
        const int mh = w >> 2;                     // row-half role
        const int srow = tid >> 3, sq = tid & 7;   // staging: 8 thr/row
        // ---- phase 1: xp slabs (r11 k1 body @ 8 waves) ----
        {
            bf16x8 wb[4][4];
            float bias[4];
            #pragma unroll
            for (int nt = 0; nt < 4; ++nt) {
                const int u = nrole * 64 + nt * 16 + c;
                #pragma unroll
                for (int kt = 0; kt < 4; ++kt)
                    wb[nt][kt] = loadf8(&Wih[(size_t)u * II + kt * 32 + g * 8]);
                bias[nt] = bih[u] + bhh[u];
            }
            for (int s = 0; s < 32; ++s) {
                const size_t rowbase = (size_t)b * TT + (size_t)s * 64;
                #pragma unroll
                for (int t2 = 0; t2 < 2; ++t2) {
                    int n = sq * 2 + t2;           // 16B chunk 0..15
                    bf16x8 v = loadf8(&x[(rowbase + srow) * II + n * 8]);
                    int off = srow * 128 + ((n * 8) ^ ((srow & 7) << 3));
                    *reinterpret_cast<bf16x8*>(&lds16[off]) = v;
                }
                __syncthreads();
                #pragma unroll
                for (int mi = 0; mi < 2; ++mi) {
                    const int mt = mh * 2 + mi;
                    const int row = mt * 16 + c;
                    bf16x8 af[4];
                    #pragma unroll
                    for (int kt = 0; kt < 4; ++kt)
                        af[kt] = *reinterpret_cast<const bf16x8*>(
                            &lds16[row * 128 + ((kt * 32 + g * 8) ^ ((c & 7) << 3))]);
                    f32x4 acc[4];
                    #pragma unroll
                    for (int nt = 0; nt < 4; ++nt) acc[nt] = (f32x4){0.f,0.f,0.f,0.f};
                    #pragma unroll
                    for (int kt = 0; kt < 4; ++kt)
                        #pragma unroll
                        for (int nt = 0; nt < 4; ++nt)
                            acc[nt] = MFMA16(af[kt], wb[nt][kt], acc[nt]);
                    #pragma unroll
                    for (int nt = 0; nt < 4; ++nt)
                        #pragma unroll
                        for (int r = 0; r < 4; ++r)
                            outH[(rowbase + mt * 16 + g * 4 + r) * UU
                                 + nrole * 64 + nt * 16 + c] = acc[nt][r] + bias[nt];
                }
                asm volatile("s_waitcnt vmcnt(0)" ::: "memory");
                __syncthreads();
                if (tid == 0)
                    __hip_atomic_store(&xpdone[b], s + 1, __ATOMIC_RELEASE,
                                       __HIP_MEMORY_SCOPE_AGENT);
                __syncthreads();
            }
        }
        // ---- phase 2: readout + mask fix-up (r11 k3 body @ 8 waves) ----
        {
            bf16x8 wb[2][8];
            float bias[2];
            #pragma unroll
            for (int nt = 0; nt < 2; ++nt) {
                const int o = nrole * 32 + nt * 16 + c;
                #pragma unroll
                for (int kt = 0; kt < 8; ++kt)
                    wb[nt][kt] = loadf8(&Wfc[(size_t)o * UU + kt * 32 + g * 8]);
                bias[nt] = bfc[o];
            }
            float* hraw = outH;
            for (int s = 0; s < 32; ++s) {
                while (__hip_atomic_load(&prog[b], __ATOMIC_ACQUIRE,
                                         __HIP_MEMORY_SCOPE_AGENT) < s + 1)
                    __builtin_amdgcn_s_sleep(8);
                const size_t rowbase = (size_t)b * TT + (size_t)s * 64;
                #pragma unroll
                for (int t2 = 0; t2 < 4; ++t2) {
                    int n = sq * 4 + t2;           // 16B chunk 0..31
                    bf16x8 v = loadf8(&hraw[(rowbase + srow) * UU + n * 8]);
                    int off = srow * 256 + ((n * 8) ^ ((srow & 7) << 3));
                    *reinterpret_cast<bf16x8*>(&lds16[off]) = v;
                }
                __syncthreads();
                // raw values staged: zero killed units in global hs output
                if (tid < 128) {
                    int r = tid >> 1, col = (tid & 1) ? 7 : 3;
                    hraw[(rowbase + r) * UU + col] = 0.f;
                }
                #pragma unroll
                for (int mi = 0; mi < 2; ++mi) {
                    const int mt = mh * 2 + mi;
                    const int row = mt * 16 + c;
                    f32x4 acc[2];
                    acc[0] = (f32x4){0.f,0.f,0.f,0.f};
                    acc[1] = (f32x4){0.f,0.f,0.f,0.f};
                    #pragma unroll
                    for (int kt = 0; kt < 8; ++kt) {
                        bf16x8 af = *reinterpret_cast<const bf16x8*>(
                            &lds16[row * 256 + ((kt * 32 + g * 8) ^ ((c & 7) << 3))]);
                        acc[0] = MFMA16(af, wb[0][kt], acc[0]);
                        acc[1] = MFMA16(af, wb[1][kt], acc[1]);
                    }
                    #pragma unroll
                    for (int nt = 0; nt < 2; ++nt)
                        #pragma unroll
                        for (int r = 0; r < 4; ++r)
                            outR[(rowbase + mt * 16 + g * 4 + r) * OO
                                 + nrole * 32 + nt * 16 + c] = acc[nt][r] + bias[nt];
                }
                __syncthreads();
            }
        }
    }
}

extern "C" void kernel_launch(void* const* d_in, const int* in_sizes, int n_in,
                              void* d_out, int out_size, void* d_ws, size_t ws_size,
                              hipStream_t stream) {
    const float* x   = (const float*)d_in[0];
    const float* Wih = (const float*)d_in[1];
    const float* Whh = (const float*)d_in[2];
    const float* bih = (const float*)d_in[3];
    const float* bhh = (const float*)d_in[4];
    const float* Wfc = (const float*)d_in[5];
    const float* bfc = (const float*)d_in[6];
    float* outR = (float*)d_out;                       // readouts [B,T,O]
    float* outH = outR + (size_t)BB * TT * OO;         // hs       [B,T,U]
    int* flags = (int*)d_ws;                           // prog[128], xpdone[128]

    hipMemsetAsync(d_ws, 0, 1024, stream);
    k_all<<<256, 512, 0, stream>>>(x, Wih, Whh, bih, bhh, Wfc, bfc,
                                   outR, outH, flags);
}

// Round 14
// 2376.211 us; speedup vs baseline: 1.0209x; 1.0209x over previous
//
#include <hip/hip_runtime.h>
#include <math.h>

#define BB 128
#define TT 2048
#define II 128
#define UU 256
#define OO 128

typedef __attribute__((ext_vector_type(8))) short bf16x8;
typedef __attribute__((ext_vector_type(4))) float f32x4;

#define MFMA16(a, b, cacc) __builtin_amdgcn_mfma_f32_16x16x32_bf16(a, b, cacc, 0, 0, 0)

// LDS-only barrier (rule 18): orders LDS ops without draining vmcnt.
__device__ __forceinline__ void bar_lds() {
    __builtin_amdgcn_sched_barrier(0);
    asm volatile("s_waitcnt lgkmcnt(0)" ::: "memory");
    __builtin_amdgcn_s_barrier();
    __builtin_amdgcn_sched_barrier(0);
}

// float -> bf16 round-to-nearest-even
__device__ __forceinline__ short f2bf(float f) {
    unsigned u = __float_as_uint(f);
    unsigned r = (u + 0x7FFFu + ((u >> 16) & 1u)) >> 16;
    return (short)r;
}

__device__ __forceinline__ bf16x8 loadf8(const float* p) {
    float4 va = *reinterpret_cast<const float4*>(p);
    float4 vb = *reinterpret_cast<const float4*>(p + 4);
    bf16x8 v;
    v[0] = f2bf(va.x); v[1] = f2bf(va.y); v[2] = f2bf(va.z); v[3] = f2bf(va.w);
    v[4] = f2bf(vb.x); v[5] = f2bf(vb.y); v[6] = f2bf(vb.z); v[7] = f2bf(vb.w);
    return v;
}

// ---------------- Persistent fused kernel, 1 block/CU ---------------------
// 256 blocks x 512 thr. 88 KB static LDS forces occupancy 1 block/CU, so
// with grid == CU count every block owns a CU: recurrence blocks (0-127)
// and worker blocks (128-255) never share a matrix pipe (r13's failure).
//   rec block b:  r8-exact recurrence (546 ns/step) + xpdone[b] gate per
//                 64-step slab + prog[b] release per slab.
//   worker b:     phase 1: xp slabs (r11 k1 body, 256 thr, 0-conflict
//                 staging) -> xpdone[b]; phase 2: readout + mask fix-up
//                 (r11 k3 body) gated on prog[b].
// xp / h_raw / hs share outH exactly as r8-r11 (validated). Cross-XCD
// visibility via AGENT-scope acquire/release (r13-validated).
__global__ __launch_bounds__(512, 1) void k_all(
    const float* __restrict__ x, const float* __restrict__ Wih,
    const float* __restrict__ Whh, const float* __restrict__ bih,
    const float* __restrict__ bhh, const float* __restrict__ Wfc,
    const float* __restrict__ bfc, float* __restrict__ outR,
    float* __restrict__ outH, int* __restrict__ flags)
{
    __shared__ __align__(16) short lds16[45056];   // 88 KB -> 1 block/CU
    const int tid = threadIdx.x;
    const int w = tid >> 6;
    const int lane = tid & 63;
    const int g = lane >> 4;
    const int c = lane & 15;
    int* prog   = flags;          // [128] h_raw slabs completed
    int* xpdone = flags + 128;    // [128] xp slabs completed

    if (blockIdx.x < 128) {
        // ================= recurrence block (batch b) =================
        const int b = blockIdx.x;
        short* hbuf = lds16;                       // 2 x 256 bf16
        bf16x8 bq[2][8];
        #pragma unroll
        for (int q2 = 0; q2 < 2; ++q2) {
            const int ub = w * 32 + q2 * 16 + c;
            #pragma unroll
            for (int kt = 0; kt < 8; ++kt)
                bq[q2][kt] = loadf8(&Whh[(size_t)ub * UU + kt * 32 + g * 8]);
        }
        const int q = g & 1;
        const int uxp = w * 32 + q * 16 + c;
        const bool gl = (g < 2);
        const bool kill = (uxp == 3) || (uxp == 7);
        if (tid < 256) reinterpret_cast<int*>(hbuf)[tid] = 0;
        __syncthreads();

        float* rowp = outH + (size_t)b * (size_t)TT * UU;
        while (__hip_atomic_load(&xpdone[b], __ATOMIC_ACQUIRE,
                                 __HIP_MEMORY_SCOPE_AGENT) < 1)
            __builtin_amdgcn_s_sleep(8);
        float xpv = rowp[uxp];
        float xpn = rowp[UU + uxp];

        auto step = [&](int t, int p) {
            int tn = t + 2; tn = (tn < TT) ? tn : (TT - 1);
            if ((tn & 63) == 0) {                  // entering xp slab tn>>6
                const int need = (tn >> 6) + 1;
                while (__hip_atomic_load(&xpdone[b], __ATOMIC_ACQUIRE,
                                         __HIP_MEMORY_SCOPE_AGENT) < need)
                    __builtin_amdgcn_s_sleep(2);
            }
            float xpn2 = rowp[(size_t)tn * UU + uxp];
            const bf16x8* hb = reinterpret_cast<const bf16x8*>(hbuf + p * 256);
            f32x4 acc0[4], acc1[4];
            #pragma unroll
            for (int i = 0; i < 4; ++i) {
                acc0[i] = (f32x4){0.f, 0.f, 0.f, 0.f};
                acc1[i] = (f32x4){0.f, 0.f, 0.f, 0.f};
            }
            #pragma unroll
            for (int kt = 0; kt < 8; ++kt) {
                bf16x8 a = hb[kt * 4 + g];
                acc0[kt & 3] = MFMA16(a, bq[0][kt], acc0[kt & 3]);
                acc1[kt & 3] = MFMA16(a, bq[1][kt], acc1[kt & 3]);
            }
            float d0 = (acc0[0][0] + acc0[1][0]) + (acc0[2][0] + acc0[3][0]);
            float d1 = (acc1[0][0] + acc1[1][0]) + (acc1[2][0] + acc1[3][0]);
            float Dres = q ? d1 : d0;
            float s = Dres + xpv;
            float hr = 1.0f - 2.0f / (__expf(2.0f * s) + 1.0f);
            if (gl) {
                rowp[(size_t)t * UU + uxp] = hr;                 // h_raw
            } else {
                hbuf[(p ^ 1) * 256 + uxp] = kill ? (short)0 : f2bf(hr);
            }
            const bool flag = ((t & 63) == 63);
            if (flag) asm volatile("s_waitcnt vmcnt(0)" ::: "memory");
            bar_lds();
            if (flag && tid == 0)
                __hip_atomic_store(&prog[b], (t >> 6) + 1, __ATOMIC_RELEASE,
                                   __HIP_MEMORY_SCOPE_AGENT);
            xpv = xpn; xpn = xpn2;
        };
        for (int t = 0; t < TT; t += 2) { step(t, 0); step(t + 1, 1); }
    } else {
        // ================= worker block (batch b) =================
        // r11 bodies verbatim: 256 active threads (waves 0-3); waves 4-7
        // only execute matching barriers. Staging 4 thr/row (0 conflicts).
        const int b = blockIdx.x - 128;
        const bool act = (tid < 256);
        const int srow = tid >> 2, sq = tid & 3;
        // ---- phase 1: xp slabs (r11 k1 body) ----
        {
            bf16x8 wb[4][4];
            float bias[4];
            if (act) {
                #pragma unroll
                for (int nt = 0; nt < 4; ++nt) {
                    const int u = w * 64 + nt * 16 + c;
                    #pragma unroll
                    for (int kt = 0; kt < 4; ++kt)
                        wb[nt][kt] = loadf8(&Wih[(size_t)u * II + kt * 32 + g * 8]);
                    bias[nt] = bih[u] + bhh[u];
                }
            }
            for (int s = 0; s < 32; ++s) {
                const size_t rowbase = (size_t)b * TT + (size_t)s * 64;
                if (act) {
                    #pragma unroll
                    for (int t2 = 0; t2 < 4; ++t2) {
                        int n = sq * 4 + t2;       // 16B chunk 0..15
                        bf16x8 v = loadf8(&x[(rowbase + srow) * II + n * 8]);
                        int off = srow * 128 + ((n * 8) ^ ((srow & 7) << 3));
                        *reinterpret_cast<bf16x8*>(&lds16[off]) = v;
                    }
                }
                __syncthreads();
                if (act) {
                    #pragma unroll
                    for (int mt = 0; mt < 4; ++mt) {
                        const int row = mt * 16 + c;
                        bf16x8 af[4];
                        #pragma unroll
                        for (int kt = 0; kt < 4; ++kt)
                            af[kt] = *reinterpret_cast<const bf16x8*>(
                                &lds16[row * 128 + ((kt * 32 + g * 8) ^ ((c & 7) << 3))]);
                        f32x4 acc[4];
                        #pragma unroll
                        for (int nt = 0; nt < 4; ++nt) acc[nt] = (f32x4){0.f,0.f,0.f,0.f};
                        #pragma unroll
                        for (int kt = 0; kt < 4; ++kt)
                            #pragma unroll
                            for (int nt = 0; nt < 4; ++nt)
                                acc[nt] = MFMA16(af[kt], wb[nt][kt], acc[nt]);
                        #pragma unroll
                        for (int nt = 0; nt < 4; ++nt)
                            #pragma unroll
                            for (int r = 0; r < 4; ++r)
                                outH[(rowbase + mt * 16 + g * 4 + r) * UU
                                     + w * 64 + nt * 16 + c] = acc[nt][r] + bias[nt];
                    }
                }
                asm volatile("s_waitcnt vmcnt(0)" ::: "memory");
                __syncthreads();
                if (tid == 0)
                    __hip_atomic_store(&xpdone[b], s + 1, __ATOMIC_RELEASE,
                                       __HIP_MEMORY_SCOPE_AGENT);
                __syncthreads();
            }
        }
        // ---- phase 2: readout + mask fix-up (r11 k3 body) ----
        {
            bf16x8 wb[2][8];
            float bias[2];
            if (act) {
                #pragma unroll
                for (int nt = 0; nt < 2; ++nt) {
                    const int o = w * 32 + nt * 16 + c;
                    #pragma unroll
                    for (int kt = 0; kt < 8; ++kt)
                        wb[nt][kt] = loadf8(&Wfc[(size_t)o * UU + kt * 32 + g * 8]);
                    bias[nt] = bfc[o];
                }
            }
            float* hraw = outH;
            for (int s = 0; s < 32; ++s) {
                while (__hip_atomic_load(&prog[b], __ATOMIC_ACQUIRE,
                                         __HIP_MEMORY_SCOPE_AGENT) < s + 1)
                    __builtin_amdgcn_s_sleep(8);
                const size_t rowbase = (size_t)b * TT + (size_t)s * 64;
                if (act) {
                    #pragma unroll
                    for (int t2 = 0; t2 < 8; ++t2) {
                        int n = sq * 8 + t2;       // 16B chunk 0..31
                        bf16x8 v = loadf8(&hraw[(rowbase + srow) * UU + n * 8]);
                        int off = srow * 256 + ((n * 8) ^ ((srow & 7) << 3));
                        *reinterpret_cast<bf16x8*>(&lds16[off]) = v;
                    }
                }
                __syncthreads();
                if (tid < 128) {
                    int r = tid >> 1, col = (tid & 1) ? 7 : 3;
                    hraw[(rowbase + r) * UU + col] = 0.f;
                }
                if (act) {
                    #pragma unroll
                    for (int mt = 0; mt < 4; ++mt) {
                        const int row = mt * 16 + c;
                        f32x4 acc[2];
                        acc[0] = (f32x4){0.f,0.f,0.f,0.f};
                        acc[1] = (f32x4){0.f,0.f,0.f,0.f};
                        #pragma unroll
                        for (int kt = 0; kt < 8; ++kt) {
                            bf16x8 af = *reinterpret_cast<const bf16x8*>(
                                &lds16[row * 256 + ((kt * 32 + g * 8) ^ ((c & 7) << 3))]);
                            acc[0] = MFMA16(af, wb[0][kt], acc[0]);
                            acc[1] = MFMA16(af, wb[1][kt], acc[1]);
                        }
                        #pragma unroll
                        for (int nt = 0; nt < 2; ++nt)
                            #pragma unroll
                            for (int r = 0; r < 4; ++r)
                                outR[(rowbase + mt * 16 + g * 4 + r) * OO
                                     + w * 32 + nt * 16 + c] = acc[nt][r] + bias[nt];
                    }
                }
                __syncthreads();
            }
        }
    }
}

extern "C" void kernel_launch(void* const* d_in, const int* in_sizes, int n_in,
                              void* d_out, int out_size, void* d_ws, size_t ws_size,
                              hipStream_t stream) {
    const float* x   = (const float*)d_in[0];
    const float* Wih = (const float*)d_in[1];
    const float* Whh = (const float*)d_in[2];
    const float* bih = (const float*)d_in[3];
    const float* bhh = (const float*)d_in[4];
    const float* Wfc = (const float*)d_in[5];
    const float* bfc = (const float*)d_in[6];
    float* outR = (float*)d_out;                       // readouts [B,T,O]
    float* outH = outR + (size_t)BB * TT * OO;         // hs       [B,T,U]
    int* flags = (int*)d_ws;                           // prog[128], xpdone[128]

    hipMemsetAsync(d_ws, 0, 1024, stream);
    k_all<<<256, 512, 0, stream>>>(x, Wih, Whh, bih, bhh, Wfc, bfc,
                                   outR, outH, flags);
}

// Round 15
// 1257.707 us; speedup vs baseline: 1.9288x; 1.8893x over previous
//
#include <hip/hip_runtime.h>
#include <math.h>

#define BB 128
#define TT 2048
#define II 128
#define UU 256
#define OO 128

typedef __attribute__((ext_vector_type(8))) short bf16x8;
typedef __attribute__((ext_vector_type(4))) float f32x4;

#define MFMA16(a, b, cacc) __builtin_amdgcn_mfma_f32_16x16x32_bf16(a, b, cacc, 0, 0, 0)

// LDS-only barrier (rule 18): orders LDS ops without draining vmcnt.
__device__ __forceinline__ void bar_lds() {
    __builtin_amdgcn_sched_barrier(0);
    asm volatile("s_waitcnt lgkmcnt(0)" ::: "memory");
    __builtin_amdgcn_s_barrier();
    __builtin_amdgcn_sched_barrier(0);
}

// float -> bf16 round-to-nearest-even
__device__ __forceinline__ short f2bf(float f) {
    unsigned u = __float_as_uint(f);
    unsigned r = (u + 0x7FFFu + ((u >> 16) & 1u)) >> 16;
    return (short)r;
}

__device__ __forceinline__ bf16x8 loadf8(const float* p) {
    float4 va = *reinterpret_cast<const float4*>(p);
    float4 vb = *reinterpret_cast<const float4*>(p + 4);
    bf16x8 v;
    v[0] = f2bf(va.x); v[1] = f2bf(va.y); v[2] = f2bf(va.z); v[3] = f2bf(va.w);
    v[4] = f2bf(vb.x); v[5] = f2bf(vb.y); v[6] = f2bf(vb.z); v[7] = f2bf(vb.w);
    return v;
}

// ---------------- Kernel 1: input projection as MFMA GEMM -----------------
// xp[row,u] = x[row,:].Wih[u,:] + bih[u] + bhh[u].  M=262144, N=256, K=128.
// 256 thr = 4 waves; tile = 64 rows. Wave w owns n-range w*64 (4 n-tiles).
// x tile staged bf16 in LDS with XOR swizzle; ~HBM floor (validated r11).
__global__ __launch_bounds__(256, 2) void k_inproj(
    const float* __restrict__ x, const float* __restrict__ Wih,
    const float* __restrict__ bih, const float* __restrict__ bhh,
    float* __restrict__ xp)
{
    __shared__ __align__(16) short xs[64 * 128];   // 16 KB bf16, swizzled
    const int tid = threadIdx.x;
    const int w = tid >> 6;
    const int lane = tid & 63;
    const int g = lane >> 4;
    const int c = lane & 15;
    bf16x8 wb[4][4];
    float bias[4];
    #pragma unroll
    for (int nt = 0; nt < 4; ++nt) {
        const int u = w * 64 + nt * 16 + c;
        #pragma unroll
        for (int kt = 0; kt < 4; ++kt)
            wb[nt][kt] = loadf8(&Wih[(size_t)u * II + kt * 32 + g * 8]);
        bias[nt] = bih[u] + bhh[u];
    }
    const int srow = tid >> 2, sq = tid & 3;       // staging: 4 thr/row
    const int ntiles = (BB * TT) / 64;             // 4096
    for (int tile = blockIdx.x; tile < ntiles; tile += gridDim.x) {
        const size_t rowbase = (size_t)tile * 64;
        #pragma unroll
        for (int t2 = 0; t2 < 4; ++t2) {
            int n = sq * 4 + t2;                   // 16B chunk index 0..15
            const float* src = &x[(rowbase + srow) * II + n * 8];
            bf16x8 v = loadf8(src);
            int off = srow * 128 + ((n * 8) ^ ((srow & 7) << 3));
            *reinterpret_cast<bf16x8*>(&xs[off]) = v;
        }
        __syncthreads();
        #pragma unroll
        for (int mt = 0; mt < 4; ++mt) {
            const int row = mt * 16 + c;
            bf16x8 af[4];
            #pragma unroll
            for (int kt = 0; kt < 4; ++kt)
                af[kt] = *reinterpret_cast<const bf16x8*>(
                    &xs[row * 128 + ((kt * 32 + g * 8) ^ ((c & 7) << 3))]);
            f32x4 acc[4];
            #pragma unroll
            for (int nt = 0; nt < 4; ++nt) acc[nt] = (f32x4){0.f,0.f,0.f,0.f};
            #pragma unroll
            for (int kt = 0; kt < 4; ++kt)
                #pragma unroll
                for (int nt = 0; nt < 4; ++nt)
                    acc[nt] = MFMA16(af[kt], wb[nt][kt], acc[nt]);
            #pragma unroll
            for (int nt = 0; nt < 4; ++nt)
                #pragma unroll
                for (int r = 0; r < 4; ++r)
                    xp[(rowbase + mt * 16 + g * 4 + r) * UU + w * 64 + nt * 16 + c]
                        = acc[nt][r] + bias[nt];
        }
        __syncthreads();
    }
}

// ---------------- Kernel 2: serial recurrence (r8 body, 546 ns/step) ------
// 1 block/batch, 512 thr = 8 waves (2/SIMD). h (bf16, replicated A) x
// W_hh bf16 B fragments; 16 MFMA into 8 independent acc slots (depth 2).
// Lane owns u = w*32+(g&1)*16+(lane&15) via C/D col=lane&15. g<2 lanes
// write h_raw (fp32) to global; g>=2 write masked bf16 LDS carry.
// Step floor ~1310 cyc: matrix pipe ~520-620 + LDS h-exchange + tanh +
// barrier skew; 8 structural variants (r4-r14) all >= this.
__global__ __launch_bounds__(512, 2) void k_rnn(
    const float* __restrict__ Whh, float* __restrict__ xph)
{
    __shared__ __align__(16) short hbuf[2 * 256];  // 2 x 256 bf16 = 1 KB
    const int tid = threadIdx.x;
    const int w = tid >> 6;
    const int lane = tid & 63;
    const int g = lane >> 4;
    const int c = lane & 15;
    bf16x8 bq[2][8];
    #pragma unroll
    for (int q2 = 0; q2 < 2; ++q2) {
        const int ub = w * 32 + q2 * 16 + c;
        #pragma unroll
        for (int kt = 0; kt < 8; ++kt)
            bq[q2][kt] = loadf8(&Whh[(size_t)ub * UU + kt * 32 + g * 8]);
    }
    const int q = g & 1;
    const int uxp = w * 32 + q * 16 + c;
    const bool gl = (g < 2);
    const bool kill = (uxp == 3) || (uxp == 7);

    if (tid < 256) reinterpret_cast<int*>(hbuf)[tid] = 0;
    __syncthreads();

    float* rowp = xph + (size_t)blockIdx.x * (size_t)TT * UU;
    float xpv = rowp[uxp];
    float xpn = rowp[UU + uxp];

    auto step = [&](int t, int p) {
        int tn = t + 2; tn = (tn < TT) ? tn : (TT - 1);
        float xpn2 = rowp[(size_t)tn * UU + uxp];
        const bf16x8* hb = reinterpret_cast<const bf16x8*>(hbuf + p * 256);
        f32x4 acc0[4], acc1[4];
        #pragma unroll
        for (int i = 0; i < 4; ++i) {
            acc0[i] = (f32x4){0.f, 0.f, 0.f, 0.f};
            acc1[i] = (f32x4){0.f, 0.f, 0.f, 0.f};
        }
        #pragma unroll
        for (int kt = 0; kt < 8; ++kt) {
            bf16x8 a = hb[kt * 4 + g];
            acc0[kt & 3] = MFMA16(a, bq[0][kt], acc0[kt & 3]);
            acc1[kt & 3] = MFMA16(a, bq[1][kt], acc1[kt & 3]);
        }
        float d0 = (acc0[0][0] + acc0[1][0]) + (acc0[2][0] + acc0[3][0]);
        float d1 = (acc1[0][0] + acc1[1][0]) + (acc1[2][0] + acc1[3][0]);
        float Dres = q ? d1 : d0;
        float s = Dres + xpv;
        float hr = 1.0f - 2.0f / (__expf(2.0f * s) + 1.0f);
        if (gl) {
            rowp[(size_t)t * UU + uxp] = hr;                    // h_raw (fp32)
        } else {
            hbuf[(p ^ 1) * 256 + uxp] = kill ? (short)0 : f2bf(hr);
        }
        bar_lds();
        xpv = xpn; xpn = xpn2;
    };
    for (int t = 0; t < TT; t += 2) { step(t, 0); step(t + 1, 1); }
}

// ---------------- Kernel 3: readout as MFMA GEMM + mask fix-up ------------
// readout[row,o] = h_raw[row,:].Wfc[o,:] + bfc[o].  M=262144, N=128, K=256.
// h_raw staged bf16 swizzled; cols {3,7} of global h_raw zeroed in place so
// the hs output becomes the masked hidden state. ~HBM floor (validated r11).
__global__ __launch_bounds__(256, 2) void k_readout(
    const float* __restrict__ Wfc, const float* __restrict__ bfc,
    float* __restrict__ hraw, float* __restrict__ outR)
{
    __shared__ __align__(16) short hs[64 * 256];   // 32 KB bf16, swizzled
    const int tid = threadIdx.x;
    const int w = tid >> 6;
    const int lane = tid & 63;
    const int g = lane >> 4;
    const int c = lane & 15;
    bf16x8 wb[2][8];
    float bias[2];
    #pragma unroll
    for (int nt = 0; nt < 2; ++nt) {
        const int o = w * 32 + nt * 16 + c;
        #pragma unroll
        for (int kt = 0; kt < 8; ++kt)
            wb[nt][kt] = loadf8(&Wfc[(size_t)o * UU + kt * 32 + g * 8]);
        bias[nt] = bfc[o];
    }
    const int srow = tid >> 2, sq = tid & 3;       // staging: 4 thr/row
    const int ntiles = (BB * TT) / 64;             // 4096
    for (int tile = blockIdx.x; tile < ntiles; tile += gridDim.x) {
        const size_t rowbase = (size_t)tile * 64;
        #pragma unroll
        for (int t2 = 0; t2 < 8; ++t2) {
            int n = sq * 8 + t2;                   // 16B chunk 0..31
            const float* src = &hraw[(rowbase + srow) * UU + n * 8];
            bf16x8 v = loadf8(src);
            int off = srow * 256 + ((n * 8) ^ ((srow & 7) << 3));
            *reinterpret_cast<bf16x8*>(&hs[off]) = v;
        }
        __syncthreads();
        // raw values staged: zero killed units in the global hs output
        if (tid < 128) {
            int r = tid >> 1, col = (tid & 1) ? 7 : 3;
            hraw[(rowbase + r) * UU + col] = 0.f;
        }
        #pragma unroll
        for (int mt = 0; mt < 4; ++mt) {
            const int row = mt * 16 + c;
            f32x4 acc[2];
            acc[0] = (f32x4){0.f,0.f,0.f,0.f};
            acc[1] = (f32x4){0.f,0.f,0.f,0.f};
            #pragma unroll
            for (int kt = 0; kt < 8; ++kt) {
                bf16x8 af = *reinterpret_cast<const bf16x8*>(
                    &hs[row * 256 + ((kt * 32 + g * 8) ^ ((c & 7) << 3))]);
                acc[0] = MFMA16(af, wb[0][kt], acc[0]);
                acc[1] = MFMA16(af, wb[1][kt], acc[1]);
            }
            #pragma unroll
            for (int nt = 0; nt < 2; ++nt)
                #pragma unroll
                for (int r = 0; r < 4; ++r)
                    outR[(rowbase + mt * 16 + g * 4 + r) * OO + w * 32 + nt * 16 + c]
                        = acc[nt][r] + bias[nt];
        }
        __syncthreads();
    }
}

extern "C" void kernel_launch(void* const* d_in, const int* in_sizes, int n_in,
                              void* d_out, int out_size, void* d_ws, size_t ws_size,
                              hipStream_t stream) {
    const float* x   = (const float*)d_in[0];
    const float* Wih = (const float*)d_in[1];
    const float* Whh = (const float*)d_in[2];
    const float* bih = (const float*)d_in[3];
    const float* bhh = (const float*)d_in[4];
    const float* Wfc = (const float*)d_in[5];
    const float* bfc = (const float*)d_in[6];
    float* outR = (float*)d_out;                       // readouts [B,T,O]
    float* outH = outR + (size_t)BB * TT * OO;         // hs       [B,T,U]

    k_inproj<<<512, 256, 0, stream>>>(x, Wih, bih, bhh, outH);
    k_rnn<<<128, 512, 0, stream>>>(Whh, outH);
    k_readout<<<512, 256, 0, stream>>>(Wfc, bfc, outH, outR);
}